// Round 6
// baseline (204.965 us; speedup 1.0000x reference)
//
#include <hip/hip_runtime.h>
#include <cstdint>
#include <cstddef>

typedef float f32x16 __attribute__((ext_vector_type(16)));
typedef int i32x4 __attribute__((ext_vector_type(4)));
typedef int i32x8 __attribute__((ext_vector_type(8)));

#define FP8_MAX 448.0f

// async global->LDS, 16B per lane; LDS dest is wave-uniform base + lane*16
#define GL(gp, lp)                                               \
  __builtin_amdgcn_global_load_lds(                              \
      (const __attribute__((address_space(1))) void*)(gp),       \
      (__attribute__((address_space(3))) void*)(lp), 16, 0, 0)

__device__ __forceinline__ uint32_t pack4_e4m3(float a, float b, float c, float d) {
  int p = __builtin_amdgcn_cvt_pk_fp8_f32(a, b, 0, false);
  p = __builtin_amdgcn_cvt_pk_fp8_f32(c, d, p, true);
  return (uint32_t)p;
}

// Fused rowwise quant: blocks [0,M) quantize input rows, [M,M+N) weight rows.
__global__ __launch_bounds__(256) void quant_rowwise(
    const float* __restrict__ X, const float* __restrict__ W,
    uint8_t* __restrict__ QA, uint8_t* __restrict__ QW,
    float* __restrict__ xsc, float* __restrict__ wsc, int K, int M) {
  const int row = blockIdx.x;
  const float* src;
  uint8_t* q;
  float* rec;
  if (row < M) {
    src = X + (size_t)row * K; q = QA + (size_t)row * K; rec = xsc + row;
  } else {
    const int r = row - M;
    src = W + (size_t)r * K; q = QW + (size_t)r * K; rec = wsc + r;
  }
  const int tid = threadIdx.x;
  const float4* __restrict__ x4 = (const float4*)src;
  float4 v[4];
  float am = 0.0f;
#pragma unroll
  for (int i = 0; i < 4; ++i) {
    v[i] = x4[i * 256 + tid];
    am = fmaxf(am, fmaxf(fmaxf(fabsf(v[i].x), fabsf(v[i].y)),
                         fmaxf(fabsf(v[i].z), fabsf(v[i].w))));
  }
#pragma unroll
  for (int off = 32; off > 0; off >>= 1)
    am = fmaxf(am, __shfl_xor(am, off));
  __shared__ float smax[4];
  const int wave = tid >> 6, lane = tid & 63;
  if (lane == 0) smax[wave] = am;
  __syncthreads();
  am = fmaxf(fmaxf(smax[0], smax[1]), fmaxf(smax[2], smax[3]));
  am = fmaxf(am, 1e-12f);
  const float scale = FP8_MAX / am;  // exact IEEE div (no fast-math)
  if (tid == 0) rec[0] = 1.0f / scale;
  uint32_t* __restrict__ q32 = (uint32_t*)q;
#pragma unroll
  for (int i = 0; i < 4; ++i) {
    float a = fminf(fmaxf(v[i].x * scale, -FP8_MAX), FP8_MAX);
    float b = fminf(fmaxf(v[i].y * scale, -FP8_MAX), FP8_MAX);
    float c = fminf(fmaxf(v[i].z * scale, -FP8_MAX), FP8_MAX);
    float d = fminf(fmaxf(v[i].w * scale, -FP8_MAX), FP8_MAX);
    q32[i * 256 + tid] = pack4_e4m3(a, b, c, d);
  }
}

// ---------------------------------------------------------------------------
// MX-scaled fp8 GEMM at 2x rate (all E8M0 scales = 1.0 == exact fp8 matmul),
// register-pipelined one K-tile ahead with a SINGLE frag set (WAR-safe:
// MFMA consumes operands at issue; ds_reads for t+1 overwrite after).
// Per iter t: barrier#1; STAGE(t+2); lgkmcnt(0)+SB0; 8x MFMA(frags_t);
// vmcnt(4); barrier#2; 12x ds_read frags_{t+1}.
// Safety: barrier#2 after every wave's counted vmcnt gate => buf[t+1]
// globally staged before reads; lgkmcnt(0) in iter t-1 + barrier#1(t) =>
// all waves' reads of buf[t-1] complete before STAGE overwrites it.
// 256x256 tile, 8 waves (2M x 4N), BK=64 B = one MFMA-K, 3 x 32 KiB LDS.
// Fragment layout: A/B lane l holds row/col = l&31, k = 32*(l>>5)+byte.
// C/D 32x32: col = l&31, row = (reg&3)+8*(reg>>2)+4*(l>>5) [m74/m101].
// LDS swizzle: stored[r][c] = logical[r][c ^ ((r>>1)&3)] (16B chunks),
// pre-swizzled on the GLOBAL source AND XOR'd on the ds_read (rule #21);
// slot(r&7) bijective -> conflict-free b128 reads.
// ---------------------------------------------------------------------------

#define MMS(TM, TN, A, B)                                          \
  acc[TM][TN] = __builtin_amdgcn_mfma_scale_f32_32x32x64_f8f6f4(   \
      (A), (B), acc[TM][TN], 0, 0, 0, 0x7F7F7F7F, 0, 0x7F7F7F7F);

// stage half-tile h (0:A rows 0-127, 1:A rows 128-255, 2:B 0-127, 3:B 128-255)
// of K-tile kt into buffer bi (0..2). One global_load_lds (16B/lane) per wave.
#define STAGE(h, kt, bi)                                                    \
  do {                                                                      \
    const uint8_t* sp = ((h) < 2 ? Aq + aoff : Bq + boff) +                 \
                        (size_t)((h) & 1) * 128 * K + (size_t)(kt) * 64;    \
    GL(sp, &lds[(bi) * 32768 + ((h) < 2 ? 0 : 16384) + ((h) & 1) * 8192 +  \
                w * 1024]);                                                 \
  } while (0)

__device__ __forceinline__ i32x8 ldfrag(const uint8_t* p, int off) {
  i32x4 lo = *(const i32x4*)(p + off);         // logical k-bytes 0-15
  i32x4 hi = *(const i32x4*)(p + (off ^ 16));  // logical k-bytes 16-31
  return __builtin_shufflevector(lo, hi, 0, 1, 2, 3, 4, 5, 6, 7);
}

#define READ_FRAGS(BUF)                                  \
  do {                                                   \
    const int bA_ = (BUF) * 32768;                       \
    const int bB_ = bA_ + 16384;                         \
    a0 = ldfrag(lds, bA_ + arow);                        \
    b0 = ldfrag(lds, bB_ + brow);                        \
    b1 = ldfrag(lds, bB_ + brow + 2048);                 \
    a1 = ldfrag(lds, bA_ + arow + 2048);                 \
    a2 = ldfrag(lds, bA_ + arow + 4096);                 \
    a3 = ldfrag(lds, bA_ + arow + 6144);                 \
  } while (0)

__global__ __launch_bounds__(512, 1) void gemm_fp8(
    const uint8_t* __restrict__ Aq, const uint8_t* __restrict__ Bq,
    const float* __restrict__ xs, const float* __restrict__ wsc,
    const float* __restrict__ bias, float* __restrict__ C,
    int M, int N, int K) {
  __shared__ __align__(16) uint8_t lds[98304];
  const int tid = threadIdx.x;
  const int w = tid >> 6, lane = tid & 63;
  const int wrow = w >> 2, wcol = w & 3;

  // XCD-aware bijective swizzle: 512 WGs, 8 XCDs, 64 per XCD.
  int bid = (int)blockIdx.x;
  bid = (bid & 7) * 64 + (bid >> 3);
  const int bm = bid & 31, bn = bid >> 5;
  const int row0 = bm * 256, col0 = bn * 256;

  // staging per-lane source offsets (pre-swizzled logical chunk):
  // lane l feeds stored slot (srow=l>>2, l&3); logical chunk = (l&3)^h,
  // h = bits 1,2 of row = (l>>3)&3.
  const int srow = lane >> 2;
  const int scol = 16 * ((lane & 3) ^ ((lane >> 3) & 3));
  const size_t aoff = (size_t)(row0 + 16 * w + srow) * K + scol;
  const size_t boff = (size_t)(col0 + 16 * w + srow) * K + scol;

  // ds_read per-lane base offsets: row r = base+(lane&31); first logical
  // chunk = 2*(lane>>5); stored chunk = logical ^ ((r>>1)&3).
  const int ln31 = lane & 31;
  const int g2 = (lane >> 5) * 2;
  const int h = (ln31 >> 1) & 3;
  const int o0 = 16 * (g2 ^ h);
  const int arow = (wrow * 128 + ln31) * 64 + o0;   // + tm*2048
  const int brow = (wcol * 64 + ln31) * 64 + o0;    // + tn*2048

  f32x16 zero = {};
  f32x16 acc[4][2];
#pragma unroll
  for (int m = 0; m < 4; ++m)
#pragma unroll
    for (int n = 0; n < 2; ++n) acc[m][n] = zero;

  const int nk = K / 64;
  i32x8 a0, a1, a2, a3, b0, b1;

  // prologue: K-tile 0 -> buf 0, K-tile 1 -> buf 1; read frags_0
  STAGE(0, 0, 0); STAGE(1, 0, 0); STAGE(2, 0, 0); STAGE(3, 0, 0);
  STAGE(0, 1, 1); STAGE(1, 1, 1); STAGE(2, 1, 1); STAGE(3, 1, 1);
  asm volatile("s_waitcnt vmcnt(4)" ::: "memory");  // tile 0 staged
  __builtin_amdgcn_s_barrier();
  READ_FRAGS(0);

  for (int t = 0; t < nk; ++t) {
    const int pb = (t + 2) % 3;
    const int rb = (t + 1) % 3;
    const int pf = (t + 2 < nk) ? t + 2 : t;  // clamped tail prefetch (dead)

    __builtin_amdgcn_s_barrier();  // #1: buf[t-1] reads all confirmed done
    STAGE(0, pf, pb); STAGE(1, pf, pb); STAGE(2, pf, pb); STAGE(3, pf, pb);

    asm volatile("s_waitcnt lgkmcnt(0)" ::: "memory");  // frags_t ready
    __builtin_amdgcn_sched_barrier(0);                  // rule #18
    __builtin_amdgcn_s_setprio(1);
    MMS(0, 0, a0, b0) MMS(0, 1, a0, b1)
    MMS(1, 0, a1, b0) MMS(1, 1, a1, b1)
    MMS(2, 0, a2, b0) MMS(2, 1, a2, b1)
    MMS(3, 0, a3, b0) MMS(3, 1, a3, b1)
    __builtin_amdgcn_s_setprio(0);

    asm volatile("s_waitcnt vmcnt(4)" ::: "memory");  // own t+1 loads done
    __builtin_amdgcn_s_barrier();  // #2: buf[t+1] globally staged
    READ_FRAGS(rb);                // frags_{t+1} (dead at t=nk-1, harmless)
  }

  // epilogue: C/D 32x32 layout col=lane&31, row=(reg&3)+8*(reg>>2)+4*(lane>>5)
  const int cl = lane & 31;
  const int rtop = (lane >> 5) * 4;
#pragma unroll
  for (int tm = 0; tm < 4; ++tm) {
#pragma unroll
    for (int tn = 0; tn < 2; ++tn) {
      const int col = col0 + wcol * 64 + tn * 32 + cl;
      const float wsn = wsc[col];
      const float bb = bias[col];
      const int rowb = row0 + wrow * 128 + tm * 32 + rtop;
#pragma unroll
      for (int q = 0; q < 4; ++q) {
        const float4 xq = *(const float4*)&xs[rowb + 8 * q];
        const float xa[4] = {xq.x, xq.y, xq.z, xq.w};
#pragma unroll
        for (int j = 0; j < 4; ++j) {
          const int r = rowb + 8 * q + j;
          C[(size_t)r * N + col] = fmaf(acc[tm][tn][4 * q + j] * xa[j], wsn, bb);
        }
      }
    }
  }
}

extern "C" void kernel_launch(void* const* d_in, const int* in_sizes, int n_in,
                              void* d_out, int out_size, void* d_ws, size_t ws_size,
                              hipStream_t stream) {
  const float* input = (const float*)d_in[0];   // [M,K] fp32
  const float* weight = (const float*)d_in[1];  // [N,K] fp32
  const float* bias = (const float*)d_in[2];    // [N]   fp32
  float* out = (float*)d_out;                   // [M,N] fp32

  const int K = 4096;
  const int N = in_sizes[2];
  const int M = in_sizes[0] / K;

  uint8_t* qA = (uint8_t*)d_ws;
  uint8_t* qW = qA + (size_t)M * K;
  float* xsc = (float*)(qW + (size_t)N * K);
  float* wsc = xsc + M;

  quant_rowwise<<<M + N, 256, 0, stream>>>(input, weight, qA, qW, xsc, wsc, K, M);

  dim3 grid((M / 256) * (N / 256));
  gemm_fp8<<<grid, 512, 0, stream>>>(qA, qW, xsc, wsc, bias, out, M, N, K);
}